// Round 3
// baseline (449.013 us; speedup 1.0000x reference)
//
#include <hip/hip_runtime.h>

#define N_BATCH 8192
#define S 14
#define N_CELLS (N_BATCH * S * S)     // 1,605,632 cells
#define N_PAIRS (N_CELLS / 2)         // 802,816 pairs (2 cells = 60 floats = 240B)
#define BLOCK 256
#define GRID (N_PAIRS / BLOCK)        // 3136 blocks, exactly one pair per lane

// Each lane owns TWO adjacent cells: 240B per tensor = 15 aligned float4.
// CRITICAL vs round 2: the asm memory-clobber pin between the load burst and
// the compute phase. Without it hipcc sinks each load to its first use
// (observed VGPR=36), destroying MLP and spreading line touches over the whole
// body (L1 thrash -> FETCH 456MB > app bytes). With the pin, all 30
// global_load_dwordx4 issue up front (30-deep, 480B in flight/lane), line
// reuse distance is 1-3 instructions (L1-resident), and waits are graduated.
__global__ __launch_bounds__(BLOCK) void yolo_loss_kernel(
    const float* __restrict__ pred, const float* __restrict__ targ,
    float* __restrict__ out)
{
    const int pair = blockIdx.x * BLOCK + (int)threadIdx.x;

    const float4* p4 = reinterpret_cast<const float4*>(pred) + (size_t)pair * 15;
    const float4* t4 = reinterpret_cast<const float4*>(targ) + (size_t)pair * 15;

    float4 pv[15], tv[15];
#pragma unroll
    for (int c = 0; c < 15; ++c) pv[c] = p4[c];
#pragma unroll
    for (int c = 0; c < 15; ++c) tv[c] = t4[c];

    // Pin: loads may not sink past this point (round-0-proven idiom).
    asm volatile("" ::: "memory");

    float p[60], t[60];
#pragma unroll
    for (int c = 0; c < 15; ++c) {
        p[4 * c + 0] = pv[c].x; p[4 * c + 1] = pv[c].y;
        p[4 * c + 2] = pv[c].z; p[4 * c + 3] = pv[c].w;
        t[4 * c + 0] = tv[c].x; t[4 * c + 1] = tv[c].y;
        t[4 * c + 2] = tv[c].z; t[4 * c + 3] = tv[c].w;
    }

    const float INV14 = 1.0f / 14.0f;
    float acc = 0.0f;

#pragma unroll
    for (int cell = 0; cell < 2; ++cell) {
        const float* P = p + 30 * cell;
        const float* T = t + 30 * cell;

        const float objf = (T[4] > 0.0f) ? 1.0f : 0.0f;
        const float noof = 1.0f - objf;

        // no-object confidence loss (conf indices 4, 9)
        const float d4 = P[4] - T[4];
        const float d9 = P[9] - T[9];
        const float nooobj = noof * (d4 * d4 + d9 * d9);

        // target box (target boxes duplicated; t[5..8] unused by reference)
        const float tx = T[0] * INV14, ty = T[1] * INV14;
        const float tw = T[2], th = T[3];
        const float tx1 = tx - 0.5f * tw, ty1 = ty - 0.5f * th;
        const float tx2 = tx + 0.5f * tw, ty2 = ty + 0.5f * th;
        const float area_t = (tx2 - tx1) * (ty2 - ty1);

        float iou[2];
#pragma unroll
        for (int b = 0; b < 2; ++b) {
            const float px = P[5 * b + 0] * INV14, py = P[5 * b + 1] * INV14;
            const float pw = P[5 * b + 2], ph = P[5 * b + 3];
            const float px1 = px - 0.5f * pw, py1 = py - 0.5f * ph;
            const float px2 = px + 0.5f * pw, py2 = py + 0.5f * ph;
            const float ltx = fmaxf(px1, tx1), lty = fmaxf(py1, ty1);
            const float rbx = fminf(px2, tx2), rby = fminf(py2, ty2);
            const float wx = fmaxf(rbx - ltx, 0.0f);
            const float wy = fmaxf(rby - lty, 0.0f);
            const float inter = wx * wy;
            const float area_p = (px2 - px1) * (py2 - py1);
            iou[b] = inter / (area_p + area_t - inter);
        }

        // responsible box: jnp.argmax -> ties pick box 0
        const bool r1 = (iou[1] > iou[0]);
        const float max_iou = fmaxf(iou[0], iou[1]);

        const float pc  = r1 ? P[9] : P[4];
        const float pnc = r1 ? P[4] : P[9];
        const float contain = objf * (pc - max_iou) * (pc - max_iou);
        const float not_contain = objf * pnc * pnc;

        const float rx = r1 ? P[5] : P[0];
        const float ry = r1 ? P[6] : P[1];
        const float rw = r1 ? P[7] : P[2];
        const float rh = r1 ? P[8] : P[3];
        const float dx = rx - T[0];
        const float dy = ry - T[1];
        const float dw = sqrtf(rw) - sqrtf(T[2]);
        const float dh = sqrtf(rh) - sqrtf(T[3]);
        const float loc = objf * (dx * dx + dy * dy + dw * dw + dh * dh);

        float cls = 0.0f;
#pragma unroll
        for (int k = 10; k < 30; ++k) {
            const float d = P[k] - T[k];
            cls += d * d;
        }
        cls *= objf;

        acc += 5.0f * loc + 2.0f * contain + 0.5f * nooobj + cls + not_contain;
    }

    acc *= (1.0f / (float)N_BATCH);

    // wave reduction, then 4-wave block reduction -> one atomic per block
#pragma unroll
    for (int off = 32; off > 0; off >>= 1)
        acc += __shfl_down(acc, off, 64);

    __shared__ float wsum[BLOCK / 64];
    const int lane = threadIdx.x & 63;
    const int wid = (int)threadIdx.x >> 6;
    if (lane == 0) wsum[wid] = acc;
    __syncthreads();
    if (threadIdx.x == 0)
        atomicAdd(out, wsum[0] + wsum[1] + wsum[2] + wsum[3]);
}

extern "C" void kernel_launch(void* const* d_in, const int* in_sizes, int n_in,
                              void* d_out, int out_size, void* d_ws, size_t ws_size,
                              hipStream_t stream) {
    const float* pred = (const float*)d_in[0];
    const float* targ = (const float*)d_in[1];
    float* out = (float*)d_out;

    hipMemsetAsync(out, 0, sizeof(float), stream);

    yolo_loss_kernel<<<GRID, BLOCK, 0, stream>>>(pred, targ, out);
}

// Round 4
// 375.861 us; speedup vs baseline: 1.1946x; 1.1946x over previous
//
#include <hip/hip_runtime.h>

#define N_BATCH 8192
#define S 14
#define N_CELLS (N_BATCH * S * S)     // 1,605,632 cells
#define N_PAIRS (N_CELLS / 2)         // 802,816 pairs (2 cells = 60 floats = 240B)
#define BLOCK 256
#define GRID (N_PAIRS / BLOCK)        // 3136 blocks, exactly one pair per lane

typedef float f32x4 __attribute__((ext_vector_type(4)));

// Each lane owns TWO adjacent cells: 240B per tensor = 15 aligned float4.
// Round-3 lesson: a bare asm memory-clobber does NOT pin loads from
// const-__restrict__ memory (LLVM proves the asm can't write them and sinks
// each load to first use -> VGPR=36, no MLP, L1 thrash, FETCH > app bytes).
// Fix: ONE asm volatile taking all 30 float4s as "v" inputs -- a hard data
// dependence. All 30 global_load_dwordx4 must issue before it (30-deep MLP,
// 480B in flight/lane), so line reuse happens inside a tight burst window.
__global__ __launch_bounds__(BLOCK) void yolo_loss_kernel(
    const float* __restrict__ pred, const float* __restrict__ targ,
    float* __restrict__ out)
{
    const int pair = blockIdx.x * BLOCK + (int)threadIdx.x;

    const f32x4* p4 = reinterpret_cast<const f32x4*>(pred) + (size_t)pair * 15;
    const f32x4* t4 = reinterpret_cast<const f32x4*>(targ) + (size_t)pair * 15;

    f32x4 pv[15], tv[15];
#pragma unroll
    for (int c = 0; c < 15; ++c) pv[c] = p4[c];
#pragma unroll
    for (int c = 0; c < 15; ++c) tv[c] = t4[c];

    // Hard pin: every loaded value must be materialized in VGPRs HERE.
    asm volatile(""
        :
        : "v"(pv[0]), "v"(pv[1]), "v"(pv[2]), "v"(pv[3]), "v"(pv[4]),
          "v"(pv[5]), "v"(pv[6]), "v"(pv[7]), "v"(pv[8]), "v"(pv[9]),
          "v"(pv[10]), "v"(pv[11]), "v"(pv[12]), "v"(pv[13]), "v"(pv[14]),
          "v"(tv[0]), "v"(tv[1]), "v"(tv[2]), "v"(tv[3]), "v"(tv[4]),
          "v"(tv[5]), "v"(tv[6]), "v"(tv[7]), "v"(tv[8]), "v"(tv[9]),
          "v"(tv[10]), "v"(tv[11]), "v"(tv[12]), "v"(tv[13]), "v"(tv[14]));

    float p[60], t[60];
#pragma unroll
    for (int c = 0; c < 15; ++c) {
        p[4 * c + 0] = pv[c][0]; p[4 * c + 1] = pv[c][1];
        p[4 * c + 2] = pv[c][2]; p[4 * c + 3] = pv[c][3];
        t[4 * c + 0] = tv[c][0]; t[4 * c + 1] = tv[c][1];
        t[4 * c + 2] = tv[c][2]; t[4 * c + 3] = tv[c][3];
    }

    const float INV14 = 1.0f / 14.0f;
    float acc = 0.0f;

#pragma unroll
    for (int cell = 0; cell < 2; ++cell) {
        const float* P = p + 30 * cell;
        const float* T = t + 30 * cell;

        const float objf = (T[4] > 0.0f) ? 1.0f : 0.0f;
        const float noof = 1.0f - objf;

        // no-object confidence loss (conf indices 4, 9)
        const float d4 = P[4] - T[4];
        const float d9 = P[9] - T[9];
        const float nooobj = noof * (d4 * d4 + d9 * d9);

        // target box (target boxes duplicated; t[5..8] unused by reference)
        const float tx = T[0] * INV14, ty = T[1] * INV14;
        const float tw = T[2], th = T[3];
        const float tx1 = tx - 0.5f * tw, ty1 = ty - 0.5f * th;
        const float tx2 = tx + 0.5f * tw, ty2 = ty + 0.5f * th;
        const float area_t = (tx2 - tx1) * (ty2 - ty1);

        float iou[2];
#pragma unroll
        for (int b = 0; b < 2; ++b) {
            const float px = P[5 * b + 0] * INV14, py = P[5 * b + 1] * INV14;
            const float pw = P[5 * b + 2], ph = P[5 * b + 3];
            const float px1 = px - 0.5f * pw, py1 = py - 0.5f * ph;
            const float px2 = px + 0.5f * pw, py2 = py + 0.5f * ph;
            const float ltx = fmaxf(px1, tx1), lty = fmaxf(py1, ty1);
            const float rbx = fminf(px2, tx2), rby = fminf(py2, ty2);
            const float wx = fmaxf(rbx - ltx, 0.0f);
            const float wy = fmaxf(rby - lty, 0.0f);
            const float inter = wx * wy;
            const float area_p = (px2 - px1) * (py2 - py1);
            iou[b] = inter / (area_p + area_t - inter);
        }

        // responsible box: jnp.argmax -> ties pick box 0
        const bool r1 = (iou[1] > iou[0]);
        const float max_iou = fmaxf(iou[0], iou[1]);

        const float pc  = r1 ? P[9] : P[4];
        const float pnc = r1 ? P[4] : P[9];
        const float contain = objf * (pc - max_iou) * (pc - max_iou);
        const float not_contain = objf * pnc * pnc;

        const float rx = r1 ? P[5] : P[0];
        const float ry = r1 ? P[6] : P[1];
        const float rw = r1 ? P[7] : P[2];
        const float rh = r1 ? P[8] : P[3];
        const float dx = rx - T[0];
        const float dy = ry - T[1];
        const float dw = sqrtf(rw) - sqrtf(T[2]);
        const float dh = sqrtf(rh) - sqrtf(T[3]);
        const float loc = objf * (dx * dx + dy * dy + dw * dw + dh * dh);

        float cls = 0.0f;
#pragma unroll
        for (int k = 10; k < 30; ++k) {
            const float d = P[k] - T[k];
            cls += d * d;
        }
        cls *= objf;

        acc += 5.0f * loc + 2.0f * contain + 0.5f * nooobj + cls + not_contain;
    }

    acc *= (1.0f / (float)N_BATCH);

    // wave reduction, then 4-wave block reduction -> one atomic per block
#pragma unroll
    for (int off = 32; off > 0; off >>= 1)
        acc += __shfl_down(acc, off, 64);

    __shared__ float wsum[BLOCK / 64];
    const int lane = threadIdx.x & 63;
    const int wid = (int)threadIdx.x >> 6;
    if (lane == 0) wsum[wid] = acc;
    __syncthreads();
    if (threadIdx.x == 0)
        atomicAdd(out, wsum[0] + wsum[1] + wsum[2] + wsum[3]);
}

extern "C" void kernel_launch(void* const* d_in, const int* in_sizes, int n_in,
                              void* d_out, int out_size, void* d_ws, size_t ws_size,
                              hipStream_t stream) {
    const float* pred = (const float*)d_in[0];
    const float* targ = (const float*)d_in[1];
    float* out = (float*)d_out;

    hipMemsetAsync(out, 0, sizeof(float), stream);

    yolo_loss_kernel<<<GRID, BLOCK, 0, stream>>>(pred, targ, out);
}